// Round 10
// baseline (16907.291 us; speedup 1.0000x reference)
//
#include <hip/hip_runtime.h>

#define T_STEPS 4096
#define N_RES   2048
#define N_IN    64
#define N_OUT   64
#define LEAK    0.3f
#define NOISE_S 0.01f

#define NWG      256     // reservoir WGs (1 per CU)
#define RPW      8       // rows per WG
#define RPWAVE   2       // rows per wave (adjacent; one 8B tagged store)

typedef unsigned int uint32x4 __attribute__((ext_vector_type(4)));
typedef unsigned int uint32x2 __attribute__((ext_vector_type(2)));

// ---------------------------------------------------------------------------
// Kernel 1: it[t][n] = dot(u[t,:], W_in[n,:]) + 0.01*noise[t][n]
// ---------------------------------------------------------------------------
__global__ __launch_bounds__(256) void input_terms_kernel(
    const float* __restrict__ u, const float* __restrict__ noise,
    const float* __restrict__ W_in, float* __restrict__ it) {
  const int t = blockIdx.x;
  const int tid = threadIdx.x;
  __shared__ float su[N_IN];
  if (tid < N_IN) su[tid] = u[(size_t)t * N_IN + tid];
  __syncthreads();
  #pragma unroll
  for (int k = 0; k < N_RES / 256; ++k) {
    const int n = tid + 256 * k;
    const float4* wr = reinterpret_cast<const float4*>(W_in + (size_t)n * N_IN);
    float acc = 0.f;
    #pragma unroll
    for (int j = 0; j < N_IN / 4; ++j) {
      float4 w4 = wr[j];
      acc = fmaf(w4.x, su[4 * j + 0], acc);
      acc = fmaf(w4.y, su[4 * j + 1], acc);
      acc = fmaf(w4.z, su[4 * j + 2], acc);
      acc = fmaf(w4.w, su[4 * j + 3], acc);
    }
    it[(size_t)t * N_RES + n] = acc + NOISE_S * noise[(size_t)t * N_RES + n];
  }
}

// ---------------------------------------------------------------------------
// Kernel 2: persistent recurrence — R4 structure, ONE barrier per step.
//
// 256 WGs x 256 threads (4 waves). Wave v owns 2 ADJACENT rows r0 = 8wg+2v.
// Per step, per wave: dot products from ls[t&1] (W LDS-resident, b128
// conflict-free) -> butterfly -> lanes 0,1 tanh/leak -> write own tagged
// words directly into ls[(t+1)&1] -> lane 0 emits ONE dwordx2 tagged store
// (sc0 sc1) -> it[] record + it[t+1] prefetch (plain, overlap the poll) ->
// all threads poll two 16B groups of s_{t+1} into ls[(t+1)&1] (skip own
// WG's groups — already written locally) -> __syncthreads.
//
// Single-barrier safety: within step t, compute reads ls[A] and poll writes
// ls[B] (A=t&1, B=!A). A thread reaches its step-t+1 poll (writing ls[A])
// only after passing sync_t, which every thread passes only after finishing
// its own compute_t (program order) — so no thread still reads ls[A]. ✓
//
// Tagging: state word = fp32 bits, low 2 mantissa bits = (step & 3); WG
// skew <= 2 steps (a producer reaches step t+2 only after all WGs finished
// polling step t, transitively through its own poll of t+1), so mod-4 tags
// disambiguate; <= 3 ulp perturbation (absmax 3.9e-3 << 2.17e-2 threshold).
// A 16B poll group = two 8B stores from sibling waves of one WG; freshness
// check = all 4 words tagged. LDS fills are 16B b128 (R4-measured
// conflict-free; R8's 8B-at-16B-stride writes caused 1.4e8 conflicts).
// s_0 = zeros in LDS, never polled (memset tag 0 != first poll tag 1).
// ---------------------------------------------------------------------------
__global__ __launch_bounds__(256, 1) void reservoir_kernel(
    const float* __restrict__ W, float* __restrict__ it,
    unsigned int* sbuf) {
  const int wg = blockIdx.x;
  const int tid = threadIdx.x;
  const int wave = tid >> 6;       // 0..3
  const int lane = tid & 63;
  const int R = wg * RPW;
  const int r0 = R + wave * RPWAVE;

  __shared__ float Wl[RPW * N_RES];   // 64 KB
  __shared__ float ls[2][N_RES];      // 16 KB state double buffer

  // Stage this WG's 8 W rows into LDS once (coalesced float4).
  {
    const float4* Wg = reinterpret_cast<const float4*>(W + (size_t)R * N_RES);
    float4* Wd = reinterpret_cast<float4*>(Wl);
    #pragma unroll
    for (int k = 0; k < RPW * N_RES / 4 / 256; ++k)
      Wd[tid + 256 * k] = Wg[tid + 256 * k];
  }
  // s_0 = zeros (reset_state=True) — no polling for step 0.
  for (int idx = tid; idx < N_RES; idx += 256) ls[0][idx] = 0.f;
  __syncthreads();

  const float4* W0 = reinterpret_cast<const float4*>(Wl + (size_t)(RPWAVE * wave + 0) * N_RES);
  const float4* W1 = reinterpret_cast<const float4*>(Wl + (size_t)(RPWAVE * wave + 1) * N_RES);

  // Which of this thread's two poll groups belong to its own WG?
  // group g covers rows [4g, 4g+4); it belongs to WG g>>1.
  const bool own0 = ((tid >> 1) == wg);            // g0 = tid
  const bool own1 = (((tid + 256) >> 1) == wg);    // g1 = tid + 256
  const unsigned int own_mask = (own0 ? 1u : 0u) | (own1 ? 2u : 0u);

  // Prefetch it[0] for this wave's rows.
  float itv = 0.f;
  if (lane < RPWAVE) itv = it[r0 + lane];

  for (unsigned int t = 0; t < T_STEPS; ++t) {
    const float* cur = ls[t & 1];
    float* nxt = ls[(t + 1) & 1];
    unsigned int* swb = sbuf + ((t + 1) & 1) * N_RES;

    // ---- two dot products per wave (conflict-free b128 LDS reads) ----
    const float4* S4 = reinterpret_cast<const float4*>(cur);
    float a0 = 0.f, a1 = 0.f;
    #pragma unroll
    for (int j = 0; j < 8; ++j) {
      const float4 s4 = S4[lane + 64 * j];
      const float4 x0 = W0[lane + 64 * j];
      const float4 x1 = W1[lane + 64 * j];
      a0 = fmaf(x0.x, s4.x, a0); a0 = fmaf(x0.y, s4.y, a0);
      a0 = fmaf(x0.z, s4.z, a0); a0 = fmaf(x0.w, s4.w, a0);
      a1 = fmaf(x1.x, s4.x, a1); a1 = fmaf(x1.y, s4.y, a1);
      a1 = fmaf(x1.z, s4.z, a1); a1 = fmaf(x1.w, s4.w, a1);
    }
    #pragma unroll
    for (int off = 32; off > 0; off >>= 1) {
      a0 += __shfl_xor(a0, off);
      a1 += __shfl_xor(a1, off);
    }

    // ---- lanes 0,1: finalize own rows; write tagged words to nxt ----
    const unsigned int tg = (t + 1) & 3u;
    unsigned int pkw = 0;
    float snew = 0.f;
    if (lane < RPWAVE) {
      const float a = lane ? a1 : a0;
      const float h = tanhf(itv + a);
      const float sold = cur[r0 + lane];
      snew = (1.0f - LEAK) * sold + LEAK * h;
      pkw = (__float_as_uint(snew) & ~3u) | tg;
      nxt[r0 + lane] = __uint_as_float(pkw);  // own values: no poll round trip
    }
    // ---- lane 0: ONE tagged dwordx2 broadcast store (fire-and-forget) ----
    uint32x2 pk;
    pk[0] = __shfl(pkw, 0);
    pk[1] = __shfl(pkw, 1);
    if (lane == 0) {
      uint32x2* dst = reinterpret_cast<uint32x2*>(swb + r0);
      asm volatile("global_store_dwordx2 %0, %1, off sc0 sc1"
                   :: "v"(dst), "v"(pk) : "memory");
    }
    // ---- it[] record + next input-term prefetch (overlap the poll) ----
    if (lane < RPWAVE) {
      it[(size_t)t * N_RES + r0 + lane] = snew;   // exact state for readout
      if (t + 1 < T_STEPS)
        itv = it[(size_t)(t + 1) * N_RES + r0 + lane];
    }

    // ---- poll s_{t+1}: two 16B groups per thread, early exit ----
    if (t + 1 < T_STEPS) {
      const char* p0 = (const char*)swb + tid * 16;
      const char* p1 = p0 + 4096;
      uint32x4* nxt16 = reinterpret_cast<uint32x4*>(nxt);
      unsigned int need = 3u & ~own_mask;
      while (need) {
        uint32x4 va, vb;
        if (need == 3u) {
          asm volatile(
              "global_load_dwordx4 %0, %2, off sc0 sc1\n\t"
              "global_load_dwordx4 %1, %3, off sc0 sc1\n\t"
              "s_waitcnt vmcnt(0)"
              : "=&v"(va), "=&v"(vb) : "v"(p0), "v"(p1) : "memory");
          if ((((va[0] ^ tg) | (va[1] ^ tg) | (va[2] ^ tg) | (va[3] ^ tg)) & 3u) == 0u) {
            nxt16[tid] = va; need &= ~1u;
          }
          if ((((vb[0] ^ tg) | (vb[1] ^ tg) | (vb[2] ^ tg) | (vb[3] ^ tg)) & 3u) == 0u) {
            nxt16[tid + 256] = vb; need &= ~2u;
          }
        } else if (need == 1u) {
          asm volatile(
              "global_load_dwordx4 %0, %1, off sc0 sc1\n\t"
              "s_waitcnt vmcnt(0)"
              : "=&v"(va) : "v"(p0) : "memory");
          if ((((va[0] ^ tg) | (va[1] ^ tg) | (va[2] ^ tg) | (va[3] ^ tg)) & 3u) == 0u) {
            nxt16[tid] = va; need = 0u;
          }
        } else {
          asm volatile(
              "global_load_dwordx4 %0, %1, off sc0 sc1\n\t"
              "s_waitcnt vmcnt(0)"
              : "=&v"(vb) : "v"(p1) : "memory");
          if ((((vb[0] ^ tg) | (vb[1] ^ tg) | (vb[2] ^ tg) | (vb[3] ^ tg)) & 3u) == 0u) {
            nxt16[tid + 256] = vb; need = 0u;
          }
        }
        if (need) __builtin_amdgcn_s_sleep(1);
      }
    }
    __syncthreads();  // nxt complete; also releases cur for step-t+2 reuse
  }
}

// ---------------------------------------------------------------------------
// Kernel 3: out[t][o] = dot(states[t,:], rw[o,:]) + rb[o]
// ---------------------------------------------------------------------------
__global__ __launch_bounds__(256) void readout_kernel(
    const float* __restrict__ states, const float* __restrict__ rw,
    const float* __restrict__ rb, float* __restrict__ out) {
  const int t = blockIdx.x;
  const int tid = threadIdx.x;
  const int o = tid & 63;
  const int q = tid >> 6;  // 0..3
  __shared__ float ss[N_RES];
  #pragma unroll
  for (int k = 0; k < N_RES / 256; ++k)
    ss[tid + 256 * k] = states[(size_t)t * N_RES + tid + 256 * k];
  __syncthreads();

  const float4* r4 = reinterpret_cast<const float4*>(rw + (size_t)o * N_RES + q * 512);
  float acc = 0.f;
  #pragma unroll 8
  for (int j = 0; j < 128; ++j) {
    float4 w4 = r4[j];
    const int base = q * 512 + 4 * j;
    acc = fmaf(w4.x, ss[base + 0], acc);
    acc = fmaf(w4.y, ss[base + 1], acc);
    acc = fmaf(w4.z, ss[base + 2], acc);
    acc = fmaf(w4.w, ss[base + 3], acc);
  }
  __shared__ float red[256];
  red[tid] = acc;
  __syncthreads();
  if (tid < 64) {
    float v = red[tid] + red[tid + 64] + red[tid + 128] + red[tid + 192];
    out[(size_t)t * N_OUT + tid] = v + rb[tid];
  }
}

// ---------------------------------------------------------------------------
extern "C" void kernel_launch(void* const* d_in, const int* in_sizes, int n_in,
                              void* d_out, int out_size, void* d_ws, size_t ws_size,
                              hipStream_t stream) {
  const float* u     = (const float*)d_in[0];  // [4096, 64]
  const float* noise = (const float*)d_in[1];  // [4096, 2048]
  const float* W_in  = (const float*)d_in[2];  // [2048, 64]
  const float* W     = (const float*)d_in[3];  // [2048, 2048]
  const float* rw    = (const float*)d_in[4];  // [64, 2048]
  const float* rb    = (const float*)d_in[5];  // [64]
  float* out = (float*)d_out;                  // [4096, 64]

  float* it = (float*)d_ws;  // 32 MB: input terms, overwritten with states
  unsigned int* sbuf =
      (unsigned int*)((char*)d_ws + (size_t)T_STEPS * N_RES * sizeof(float));

  // Zero both tagged state buffers every call (0xAA poison would alias tag
  // bits; zeros are safe: stale tag = fresh-2 mod 4, never equal).
  hipMemsetAsync(sbuf, 0, 2 * N_RES * sizeof(unsigned int), stream);

  input_terms_kernel<<<T_STEPS, 256, 0, stream>>>(u, noise, W_in, it);

  void* args[] = {(void*)&W, (void*)&it, (void*)&sbuf};
  hipLaunchCooperativeKernel((void*)reservoir_kernel, dim3(NWG), dim3(256),
                             args, 0, stream);

  readout_kernel<<<T_STEPS, 256, 0, stream>>>(it, rw, rb, out);
}